// Round 2
// baseline (3254.668 us; speedup 1.0000x reference)
//
#include <hip/hip_runtime.h>
#include <hip/hip_bf16.h>

// L=256, B=32, H=8, d_head=64, m=256, feature dim 2m=512, D_MODEL=512
#define L_SEQ 256
#define B_SZ  32
#define NH    8
#define DH    64
#define DM    512
#define FD    512
#define PM    256
#define ROWS  8192
#define QKVN  2048

static __device__ __forceinline__ float b2f(__hip_bfloat16 x) { return __bfloat162float(x); }

// Inputs may be bf16 or f32 (runtime-probed flag): uniform branch per load.
static __device__ __forceinline__ float ldmix(const void* p, long i, int f32) {
  return f32 ? ((const float*)p)[i] : __bfloat162float(((const __hip_bfloat16*)p)[i]);
}
static __device__ __forceinline__ void stmix(void* p, long i, float v, int f32) {
  if (f32) ((float*)p)[i] = v;
  else     ((__hip_bfloat16*)p)[i] = __float2bfloat16(v);
}

// ---------------------------------------------------------------------------
// P0: dtype probe. bf16 N(0,1) data: no element has exponent >= 0xA0 (|x|>2^33).
// f32 data read as 16-bit halves: odd halves are uniform junk, ~37% land there.
// ---------------------------------------------------------------------------
__global__ void probe_dtype(const unsigned short* __restrict__ hbits, int* __restrict__ flag) {
  __shared__ int red[256];
  const int tid = threadIdx.x;
  int cnt = 0;
  for (int i = 0; i < 16; ++i) {
    const unsigned short u = hbits[tid * 16 + i];
    const int e = (u >> 7) & 0xFF;
    if (e >= 0xA0) ++cnt;
  }
  red[tid] = cnt; __syncthreads();
  for (int s = 128; s > 0; s >>= 1) { if (tid < s) red[tid] += red[tid + s]; __syncthreads(); }
  if (tid == 0) flag[0] = (red[0] >= 64) ? 1 : 0;
}

// ---------------------------------------------------------------------------
// K1: qkv = h @ w_qkv   [8192,512]@[512,2048] -> bf16
// ---------------------------------------------------------------------------
__global__ void gemm_qkv(const void* __restrict__ A, const void* __restrict__ B,
                         const int* __restrict__ flag, __hip_bfloat16* __restrict__ C) {
  __shared__ float As[16][64];
  __shared__ float Bs[16][64];
  const int f32 = flag[0];
  const int n0 = blockIdx.x * 64;
  const int m0 = blockIdx.y * 64;
  const int tid = threadIdx.x;   // 256
  const int tx = tid & 15, ty = tid >> 4;
  float c[4][4] = {};
  for (int k0 = 0; k0 < DM; k0 += 16) {
    {
      const int row = tid >> 2;          // 64 A-rows
      const int kk = (tid & 3) * 4;
#pragma unroll
      for (int j = 0; j < 4; ++j)
        As[kk + j][row] = ldmix(A, (long)(m0 + row) * DM + k0 + kk + j, f32);
      const int brow = tid >> 4;         // 16 B-rows
      const int bn = (tid & 15) * 4;
#pragma unroll
      for (int j = 0; j < 4; ++j)
        Bs[brow][bn + j] = ldmix(B, (long)(k0 + brow) * QKVN + n0 + bn + j, f32);
    }
    __syncthreads();
#pragma unroll
    for (int kk2 = 0; kk2 < 16; ++kk2) {
      float a[4], bb[4];
#pragma unroll
      for (int i = 0; i < 4; ++i) a[i] = As[kk2][ty * 4 + i];
#pragma unroll
      for (int j = 0; j < 4; ++j) bb[j] = Bs[kk2][tx * 4 + j];
#pragma unroll
      for (int i = 0; i < 4; ++i)
#pragma unroll
        for (int j = 0; j < 4; ++j) c[i][j] += a[i] * bb[j];
    }
    __syncthreads();
  }
#pragma unroll
  for (int i = 0; i < 4; ++i)
#pragma unroll
    for (int j = 0; j < 4; ++j)
      C[(long)(m0 + ty * 4 + i) * QKVN + n0 + tx * 4 + j] = __float2bfloat16(c[i][j]);
}

// ---------------------------------------------------------------------------
// K2: Performer features. norm(prime(x,P)) == softmax([xP,-xP]) exactly
// (the -half and -max row constants cancel under sum-normalization).
// One block per (bh_local, l); writes group-local qf/kf.
// ---------------------------------------------------------------------------
__global__ void features(const __hip_bfloat16* __restrict__ qkv, const void* __restrict__ proj,
                         const void* __restrict__ pi0, const void* __restrict__ pi1,
                         const int* __restrict__ flag, int bh0,
                         __hip_bfloat16* __restrict__ qf, __hip_bfloat16* __restrict__ kf) {
  const int f32 = flag[0];
  const int idx = blockIdx.x;        // bh_local*256 + l
  const int l = idx & 255;
  const int bhl = idx >> 8;
  const int bhg = bhl + bh0;
  const int h = bhg & 7, b = bhg >> 3;
  const int tid = threadIdx.x;       // 256
  __shared__ float xq[DH], xk1[DH], xk2[DH];
  __shared__ float red[256];

  const long rowbase = (long)(l * B_SZ + b) * QKVN + h * 256;
  if (tid < DH) {
    const float s = 0.35355339059327373f;   // 64^-0.25
    xq[tid]  = b2f(qkv[rowbase + tid]) * s;
    xk1[tid] = b2f(qkv[rowbase + 64 + tid]) * s;
    xk2[tid] = b2f(qkv[rowbase + 128 + tid]) * s;
  }
  __syncthreads();

  float xpq = 0.f, xp1 = 0.f, xp2 = 0.f;
  for (int dd = 0; dd < DH; ++dd) {
    const float p = ldmix(proj, (long)dd * PM + tid, f32);
    xpq += xq[dd] * p; xp1 += xk1[dd] * p; xp2 += xk2[dd] * p;
  }
  xp2 *= 0.7f;   // SCALE_W

  auto bmax = [&](float v) -> float {
    red[tid] = v; __syncthreads();
    for (int s = 128; s > 0; s >>= 1) { if (tid < s) red[tid] = fmaxf(red[tid], red[tid + s]); __syncthreads(); }
    const float r = red[0]; __syncthreads(); return r;
  };
  auto bsum = [&](float v) -> float {
    red[tid] = v; __syncthreads();
    for (int s = 128; s > 0; s >>= 1) { if (tid < s) red[tid] += red[tid + s]; __syncthreads(); }
    const float r = red[0]; __syncthreads(); return r;
  };

  const long obase = (long)idx * FD;
  {
    const float mx = bmax(fabsf(xpq));
    const float e1 = __expf(xpq - mx), e2 = __expf(-xpq - mx);
    const float inv = 1.f / bsum(e1 + e2);
    qf[obase + tid]       = __float2bfloat16(e1 * inv);
    qf[obase + 256 + tid] = __float2bfloat16(e2 * inv);
  }
  {
    const float p0 = ldmix(pi0, h * 256 + l, f32);
    const float p1 = ldmix(pi1, h * 256 + l, f32);
    const float mx1 = bmax(fabsf(xp1));
    const float a1 = __expf(xp1 - mx1), a2 = __expf(-xp1 - mx1);
    const float i1 = 1.f / bsum(a1 + a2);
    const float mx2 = bmax(fabsf(xp2));
    const float b1 = __expf(xp2 - mx2), b2v = __expf(-xp2 - mx2);
    const float i2 = 1.f / bsum(b1 + b2v);
    kf[obase + tid]       = __float2bfloat16(p0 * a1 * i1 + p1 * b1 * i2);
    kf[obase + 256 + tid] = __float2bfloat16(p0 * a2 * i1 + p1 * b2v * i2);
  }
}

// ---------------------------------------------------------------------------
// K3: fused flash-style causal linear attention (never materializes sc[256,256]).
// Block = (t-tile of 32 rows) x (bh). Iterates s-tiles of 64, K-chunks of 128.
// out[t,d] = SCALE * sum_{s<=t} sc[t,s] v[s,d] / (sum_{s<=t} sc[t,s] + EPS)
// ---------------------------------------------------------------------------
__global__ void flash_attn(const __hip_bfloat16* __restrict__ qf,   // [nbh,256,512]
                           const __hip_bfloat16* __restrict__ kf,   // [nbh,256,512]
                           const __hip_bfloat16* __restrict__ qkv,  // [8192,2048]
                           int bh0,
                           __hip_bfloat16* __restrict__ att) {      // [8192,512]
  const int t0 = blockIdx.x * 32;
  const int bhl = blockIdx.y;
  const int bhg = bhl + bh0;
  const int h = bhg & 7, b = bhg >> 3;
  const int tid = threadIdx.x;       // 256
  __shared__ float qfc[32][128];
  __shared__ float kfc[64][128];
  __shared__ float scL[32][64];
  __shared__ float denacc[32];
  if (tid < 32) denacc[tid] = 0.f;
  float acc[8] = {};                 // PV accumulators: 8 rows x 1 col each
  const int d = tid & 63;
  const int rq = tid >> 6;           // row-quad 0..3
  const int tx = tid & 15, ty = tid >> 4;
  const int nst = (t0 >> 6) + 1;     // s-tiles (64-wide) touching s<=t
  __syncthreads();

  for (int st = 0; st < nst; ++st) {
    const int s0 = st * 64;
    float c[2][4] = {};
    for (int ch = 0; ch < 4; ++ch) {   // K chunks of 128
      {
        const int row = tid >> 3;               // 32 qf rows
        const int c0 = (tid & 7) * 16;
        const long base = (long)(bhl * 256 + t0 + row) * FD + ch * 128 + c0;
#pragma unroll
        for (int j = 0; j < 16; ++j) qfc[row][c0 + j] = b2f(qf[base + j]);
      }
      {
        const int row = tid >> 2;               // 64 kf rows
        const int c0 = (tid & 3) * 32;
        const long base = (long)(bhl * 256 + s0 + row) * FD + ch * 128 + c0;
#pragma unroll
        for (int j = 0; j < 32; ++j) kfc[row][c0 + j] = b2f(kf[base + j]);
      }
      __syncthreads();
      for (int m = 0; m < 128; ++m) {
        const float a0 = qfc[ty * 2][m],     a1 = qfc[ty * 2 + 1][m];
        const float b0 = kfc[tx * 4][m],     b1 = kfc[tx * 4 + 1][m];
        const float b2v = kfc[tx * 4 + 2][m], b3 = kfc[tx * 4 + 3][m];
        c[0][0] += a0 * b0; c[0][1] += a0 * b1; c[0][2] += a0 * b2v; c[0][3] += a0 * b3;
        c[1][0] += a1 * b0; c[1][1] += a1 * b1; c[1][2] += a1 * b2v; c[1][3] += a1 * b3;
      }
      __syncthreads();
    }
    // masked score tile -> LDS
#pragma unroll
    for (int i = 0; i < 2; ++i)
#pragma unroll
      for (int j = 0; j < 4; ++j) {
        const int ii = ty * 2 + i, jj = tx * 4 + j;
        scL[ii][jj] = (s0 + jj <= t0 + ii) ? c[i][j] : 0.f;
      }
    __syncthreads();
    if (tid < 32) {                  // denominator row-sums
      float s = 0.f;
      for (int j = 0; j < 64; ++j) s += scL[tid][j];
      denacc[tid] += s;
    }
    __syncthreads();
    // PV: v rows streamed from qkv (coalesced over d, L2-resident)
    for (int j = 0; j < 64; ++j) {
      const float vv = b2f(qkv[(long)((s0 + j) * B_SZ + b) * QKVN + h * 256 + 192 + d]);
#pragma unroll
      for (int r = 0; r < 8; ++r) acc[r] += scL[rq * 8 + r][j] * vv;
    }
    __syncthreads();
  }
#pragma unroll
  for (int r = 0; r < 8; ++r) {
    const int i = rq * 8 + r;
    const float o = 0.125f * acc[r] / (denacc[i] + 1e-5f);   // SCALE, EPS
    att[(long)((t0 + i) * B_SZ + b) * DM + h * DH + d] = __float2bfloat16(o);
  }
}

// ---------------------------------------------------------------------------
// K4: y = LayerNorm(h + att @ w_o). One block per row (l,b).
// ---------------------------------------------------------------------------
__global__ void proj_ln(const __hip_bfloat16* __restrict__ att, const void* __restrict__ hin,
                        const void* __restrict__ wo, const void* __restrict__ gamma,
                        const void* __restrict__ beta, const int* __restrict__ flag,
                        void* __restrict__ out) {
  const int f32 = flag[0];
  const int r = blockIdx.x;
  const int tid = threadIdx.x;       // 256
  __shared__ float arow[DM];
  __shared__ float red[256];
  arow[tid]       = b2f(att[(long)r * DM + tid]);
  arow[tid + 256] = b2f(att[(long)r * DM + tid + 256]);
  __syncthreads();
  float acc0 = 0.f, acc1 = 0.f;
  for (int k = 0; k < DM; ++k) {
    const float a = arow[k];
    acc0 += a * ldmix(wo, (long)k * DM + tid, f32);
    acc1 += a * ldmix(wo, (long)k * DM + tid + 256, f32);
  }
  const float x0 = ldmix(hin, (long)r * DM + tid, f32) + acc0;
  const float x1 = ldmix(hin, (long)r * DM + tid + 256, f32) + acc1;

  red[tid] = x0 + x1; __syncthreads();
  for (int s = 128; s > 0; s >>= 1) { if (tid < s) red[tid] += red[tid + s]; __syncthreads(); }
  const float mu = red[0] * (1.f / 512.f); __syncthreads();
  red[tid] = x0 * x0 + x1 * x1; __syncthreads();
  for (int s = 128; s > 0; s >>= 1) { if (tid < s) red[tid] += red[tid + s]; __syncthreads(); }
  const float var = red[0] * (1.f / 512.f) - mu * mu; __syncthreads();
  const float rstd = rsqrtf(var + 1e-5f);

  stmix(out, (long)r * DM + tid,
        (x0 - mu) * rstd * ldmix(gamma, tid, f32) + ldmix(beta, tid, f32), f32);
  stmix(out, (long)r * DM + tid + 256,
        (x1 - mu) * rstd * ldmix(gamma, tid + 256, f32) + ldmix(beta, tid + 256, f32), f32);
}

// ---------------------------------------------------------------------------
extern "C" void kernel_launch(void* const* d_in, const int* in_sizes, int n_in,
                              void* d_out, int out_size, void* d_ws, size_t ws_size,
                              hipStream_t stream) {
  (void)in_sizes; (void)n_in; (void)out_size;
  const void* h_in  = d_in[0];
  const void* w_qkv = d_in[1];
  const void* w_o   = d_in[2];
  const void* gamma = d_in[3];
  const void* beta  = d_in[4];
  const void* pi0   = d_in[5];
  const void* pi1   = d_in[6];
  const void* proj  = d_in[7];

  // Workspace layout (bytes):
  //   qkv bf16 [8192,2048]  @ 0            33,554,432
  //   flag int              @ 33,554,432   256
  //   att bf16 [8192,512]   @ 33,554,688   8,388,608
  //   qf/kf groups          @ 41,943,296   2 * 67,108,864 / G
  char* ws = (char*)d_ws;
  __hip_bfloat16* qkv = (__hip_bfloat16*)ws;
  int* flag           = (int*)(ws + 33554432);
  __hip_bfloat16* att = (__hip_bfloat16*)(ws + 33554688);
  const size_t base = 41943296;

  int G = 32;
  for (int g : {1, 2, 4, 8, 16, 32}) {
    if (base + 2ull * (67108864ull / (unsigned)g) <= ws_size) { G = g; break; }
  }
  const long grpElems = 33554432L / G;   // bf16 elements per group buffer
  __hip_bfloat16* qf = (__hip_bfloat16*)(ws + base);
  __hip_bfloat16* kf = qf + grpElems;

  probe_dtype<<<1, 256, 0, stream>>>((const unsigned short*)h_in, flag);
  gemm_qkv<<<dim3(QKVN / 64, ROWS / 64), 256, 0, stream>>>(h_in, w_qkv, flag, qkv);

  const int nbh = 256 / G;
  for (int g = 0; g < G; ++g) {
    features<<<dim3(nbh * 256), 256, 0, stream>>>(qkv, proj, pi0, pi1, flag, g * nbh, qf, kf);
    flash_attn<<<dim3(8, nbh), 256, 0, stream>>>(qf, kf, qkv, g * nbh, att);
  }
  proj_ln<<<dim3(ROWS), 256, 0, stream>>>(att, h_in, w_o, gamma, beta, flag, (void*)d_out);
}

// Round 3
// 1027.789 us; speedup vs baseline: 3.1667x; 3.1667x over previous
//
#include <hip/hip_runtime.h>
#include <hip/hip_bf16.h>

// L=256, B=32, H=8, d_head=64, m=256, feature dim 2m=512, D_MODEL=512
#define L_SEQ 256
#define B_SZ  32
#define NH    8
#define DH    64
#define DM    512
#define FD    512
#define PM    256
#define ROWS  8192
#define QKVN  2048

typedef __bf16 bf16x8 __attribute__((ext_vector_type(8)));
typedef float f32x4 __attribute__((ext_vector_type(4)));
#define MFMA16(a, b, c) __builtin_amdgcn_mfma_f32_16x16x32_bf16((a), (b), (c), 0, 0, 0)

static __device__ __forceinline__ float b2f(__hip_bfloat16 x) { return __bfloat162float(x); }

// Inputs may be bf16 or f32 (runtime-probed flag): uniform branch per load.
static __device__ __forceinline__ float ldmix(const void* p, long i, int f32) {
  return f32 ? ((const float*)p)[i] : (float)(((const __bf16*)p)[i]);
}
static __device__ __forceinline__ void stmix(void* p, long i, float v, int f32) {
  if (f32) ((float*)p)[i] = v;
  else     ((__bf16*)p)[i] = (__bf16)v;
}

// ---------------------------------------------------------------------------
// P0: dtype probe (unchanged; round-2 validated).
// ---------------------------------------------------------------------------
__global__ void probe_dtype(const unsigned short* __restrict__ hbits, int* __restrict__ flag) {
  __shared__ int red[256];
  const int tid = threadIdx.x;
  int cnt = 0;
  for (int i = 0; i < 16; ++i) {
    const unsigned short u = hbits[tid * 16 + i];
    const int e = (u >> 7) & 0xFF;
    if (e >= 0xA0) ++cnt;
  }
  red[tid] = cnt; __syncthreads();
  for (int s = 128; s > 0; s >>= 1) { if (tid < s) red[tid] += red[tid + s]; __syncthreads(); }
  if (tid == 0) flag[0] = (red[0] >= 64) ? 1 : 0;
}

// ---------------------------------------------------------------------------
// T0: dst[n][m] = src[m][n] as bf16. grid (N/64, M/64). LDS pad 69 -> 2-way max.
// ---------------------------------------------------------------------------
__global__ __launch_bounds__(256) void transpose_bf(const void* __restrict__ src,
                                                    const int* __restrict__ flag,
                                                    __bf16* __restrict__ dst, int M, int N) {
  __shared__ float T[64][69];
  const int f32 = flag[0];
  const int n0 = blockIdx.x * 64, m0 = blockIdx.y * 64;
  const int tid = threadIdx.x;
#pragma unroll
  for (int rep = 0; rep < 16; ++rep) {
    const int i = rep * 4 + (tid >> 6), j = tid & 63;
    T[i][j] = ldmix(src, (long)(m0 + i) * N + n0 + j, f32);
  }
  __syncthreads();
#pragma unroll
  for (int rep = 0; rep < 16; ++rep) {
    const int i = rep * 4 + (tid >> 6), j = tid & 63;
    dst[(long)(n0 + i) * M + m0 + j] = (__bf16)T[j][i];
  }
}

// ---------------------------------------------------------------------------
// K1: qkv = h @ w_qkv via MFMA. Bt = w_qkv^T [2048][512]. Tile 64x64, K-chunks 128.
// LDS rows padded to 136 bf16 (272 B, stride mod-32-words = 4 -> uniform banks).
// ---------------------------------------------------------------------------
__global__ __launch_bounds__(256) void gemm_h_wqkv(const void* __restrict__ A,
                                                   const int* __restrict__ flag,
                                                   const __bf16* __restrict__ Bt,
                                                   __bf16* __restrict__ C) {
  __shared__ __bf16 At[64][136];
  __shared__ __bf16 Bts[64][136];
  const int f32 = flag[0];
  const int n0 = blockIdx.x * 64, m0 = blockIdx.y * 64;
  const int tid = threadIdx.x, lane = tid & 63, wv = tid >> 6;
  const int m = lane & 15, q = lane >> 4;
  f32x4 acc[4];
#pragma unroll
  for (int i = 0; i < 4; ++i) acc[i] = f32x4{0.f, 0.f, 0.f, 0.f};

  for (int k0 = 0; k0 < DM; k0 += 128) {
    __syncthreads();
    {
      const int r = tid >> 2, c0 = (tid & 3) * 32;
#pragma unroll
      for (int j4 = 0; j4 < 4; ++j4) {
        bf16x8 t;
#pragma unroll
        for (int e = 0; e < 8; ++e)
          t[e] = (__bf16)ldmix(A, (long)(m0 + r) * DM + k0 + c0 + j4 * 8 + e, f32);
        *reinterpret_cast<bf16x8*>(&At[r][c0 + j4 * 8]) = t;
        *reinterpret_cast<bf16x8*>(&Bts[r][c0 + j4 * 8]) =
            *reinterpret_cast<const bf16x8*>(Bt + (long)(n0 + r) * DM + k0 + c0 + j4 * 8);
      }
    }
    __syncthreads();
#pragma unroll
    for (int kk = 0; kk < 4; ++kk) {
      const bf16x8 af = *reinterpret_cast<const bf16x8*>(&At[wv * 16 + m][kk * 32 + q * 8]);
#pragma unroll
      for (int c = 0; c < 4; ++c) {
        const bf16x8 bf = *reinterpret_cast<const bf16x8*>(&Bts[c * 16 + m][kk * 32 + q * 8]);
        acc[c] = MFMA16(af, bf, acc[c]);
      }
    }
  }
#pragma unroll
  for (int r = 0; r < 4; ++r)
#pragma unroll
    for (int c = 0; c < 4; ++c)
      C[(long)(m0 + wv * 16 + q * 4 + r) * QKVN + n0 + c * 16 + m] = (__bf16)acc[c][r];
}

// ---------------------------------------------------------------------------
// K2: Performer features (unchanged from round 2 — correctness-proven).
// ---------------------------------------------------------------------------
__global__ void features(const __hip_bfloat16* __restrict__ qkv, const void* __restrict__ proj,
                         const void* __restrict__ pi0, const void* __restrict__ pi1,
                         const int* __restrict__ flag, int bh0,
                         __hip_bfloat16* __restrict__ qf, __hip_bfloat16* __restrict__ kf) {
  const int f32 = flag[0];
  const int idx = blockIdx.x;
  const int l = idx & 255;
  const int bhl = idx >> 8;
  const int bhg = bhl + bh0;
  const int h = bhg & 7, b = bhg >> 3;
  const int tid = threadIdx.x;
  __shared__ float xq[DH], xk1[DH], xk2[DH];
  __shared__ float red[256];

  const long rowbase = (long)(l * B_SZ + b) * QKVN + h * 256;
  if (tid < DH) {
    const float s = 0.35355339059327373f;   // 64^-0.25
    xq[tid]  = b2f(qkv[rowbase + tid]) * s;
    xk1[tid] = b2f(qkv[rowbase + 64 + tid]) * s;
    xk2[tid] = b2f(qkv[rowbase + 128 + tid]) * s;
  }
  __syncthreads();

  float xpq = 0.f, xp1 = 0.f, xp2 = 0.f;
  for (int dd = 0; dd < DH; ++dd) {
    const float p = ldmix(proj, (long)dd * PM + tid, f32);
    xpq += xq[dd] * p; xp1 += xk1[dd] * p; xp2 += xk2[dd] * p;
  }
  xp2 *= 0.7f;

  auto bmax = [&](float v) -> float {
    red[tid] = v; __syncthreads();
    for (int s = 128; s > 0; s >>= 1) { if (tid < s) red[tid] = fmaxf(red[tid], red[tid + s]); __syncthreads(); }
    const float r = red[0]; __syncthreads(); return r;
  };
  auto bsum = [&](float v) -> float {
    red[tid] = v; __syncthreads();
    for (int s = 128; s > 0; s >>= 1) { if (tid < s) red[tid] += red[tid + s]; __syncthreads(); }
    const float r = red[0]; __syncthreads(); return r;
  };

  const long obase = (long)idx * FD;
  {
    const float mx = bmax(fabsf(xpq));
    const float e1 = __expf(xpq - mx), e2 = __expf(-xpq - mx);
    const float inv = 1.f / bsum(e1 + e2);
    qf[obase + tid]       = __float2bfloat16(e1 * inv);
    qf[obase + 256 + tid] = __float2bfloat16(e2 * inv);
  }
  {
    const float p0 = ldmix(pi0, h * 256 + l, f32);
    const float p1 = ldmix(pi1, h * 256 + l, f32);
    const float mx1 = bmax(fabsf(xp1));
    const float a1 = __expf(xp1 - mx1), a2 = __expf(-xp1 - mx1);
    const float i1 = 1.f / bsum(a1 + a2);
    const float mx2 = bmax(fabsf(xp2));
    const float b1 = __expf(xp2 - mx2), b2v = __expf(-xp2 - mx2);
    const float i2 = 1.f / bsum(b1 + b2v);
    kf[obase + tid]       = __float2bfloat16(p0 * a1 * i1 + p1 * b1 * i2);
    kf[obase + 256 + tid] = __float2bfloat16(p0 * a2 * i1 + p1 * b2v * i2);
  }
}

// ---------------------------------------------------------------------------
// K2b: pack V transposed per head: vt[bh][d][s] (bf16), coalesced output rows.
// ---------------------------------------------------------------------------
__global__ __launch_bounds__(256) void vpack(const __bf16* __restrict__ qkv,
                                             __bf16* __restrict__ vt) {
  const int s0 = blockIdx.x * 64;
  const int bh = blockIdx.y;
  const int h = bh & 7, b = bh >> 3;
  __shared__ __bf16 T[64][72];
  const int tid = threadIdx.x;
  {
    const int s = tid >> 2, d0 = (tid & 3) * 16;
    const __bf16* vp = qkv + ((long)((s0 + s) * B_SZ + b)) * QKVN + h * 256 + 192 + d0;
#pragma unroll
    for (int j = 0; j < 16; ++j) T[d0 + j][s] = vp[j];
  }
  __syncthreads();
  {
    const int d = tid >> 2, sc = (tid & 3) * 16;
    __bf16* op = vt + ((long)bh * 64 + d) * 256 + s0 + sc;
    *reinterpret_cast<bf16x8*>(op)     = *reinterpret_cast<const bf16x8*>(&T[d][sc]);
    *reinterpret_cast<bf16x8*>(op + 8) = *reinterpret_cast<const bf16x8*>(&T[d][sc + 8]);
  }
}

// ---------------------------------------------------------------------------
// K3: MFMA flash causal linear attention. 64-row Q-tile per block, Q frags in
// registers (all K=512). S = Q.K^T via 16x16x32 MFMA; P (masked, bf16) round-
// trips through LDS (C-layout -> A-layout); PV adds a ones-column to V so the
// denominator falls out of accumulator tile 4 col 0.
// ---------------------------------------------------------------------------
__global__ __launch_bounds__(256) void flash_mfma(const __bf16* __restrict__ qf,
                                                  const __bf16* __restrict__ kf,
                                                  const __bf16* __restrict__ vt,
                                                  int bh0,
                                                  __bf16* __restrict__ att) {
  const int t0 = blockIdx.x * 64;
  const int bhl = blockIdx.y;
  const int bhg = bhl + bh0;
  const int h = bhg & 7, b = bhg >> 3;
  const int tid = threadIdx.x, lane = tid & 63, wv = tid >> 6;
  const int m = lane & 15, q = lane >> 4;
  __shared__ __bf16 Kc[64][136];   // K-feature chunk, padded stride (272 B)
  __shared__ __bf16 Vt[80][72];    // V^T tile + ones row (row 64) + zero rows
  __shared__ __bf16 Pt[64][72];    // masked P in A-operand layout

  bf16x8 qreg[16];
  {
    const __bf16* qp = qf + ((long)(bhl * 256 + t0 + wv * 16 + m)) * FD + q * 8;
#pragma unroll
    for (int ks = 0; ks < 16; ++ks)
      qreg[ks] = *reinterpret_cast<const bf16x8*>(qp + ks * 32);
  }
  f32x4 oacc[5];
#pragma unroll
  for (int i = 0; i < 5; ++i) oacc[i] = f32x4{0.f, 0.f, 0.f, 0.f};

  const int nst = (t0 >> 6) + 1;
  for (int st = 0; st < nst; ++st) {
    const int s0 = st * 64;
    f32x4 sacc[4];
#pragma unroll
    for (int i = 0; i < 4; ++i) sacc[i] = f32x4{0.f, 0.f, 0.f, 0.f};
    __syncthreads();   // all waves done reading Kc/Vt from previous s-tile
    {
      const int d = tid >> 2, sc = (tid & 3) * 16;
      const __bf16* vp = vt + ((long)bhg * 64 + d) * 256 + s0 + sc;
      *reinterpret_cast<bf16x8*>(&Vt[d][sc])     = *reinterpret_cast<const bf16x8*>(vp);
      *reinterpret_cast<bf16x8*>(&Vt[d][sc + 8]) = *reinterpret_cast<const bf16x8*>(vp + 8);
      if (tid < 64) Vt[64][tid] = (__bf16)1.0f;
      if (st == 0)
        for (int z = tid; z < 15 * 64; z += 256) Vt[65 + (z >> 6)][z & 63] = (__bf16)0.f;
    }
    for (int ch = 0; ch < 4; ++ch) {
      if (ch) __syncthreads();
      {
        const int r = tid >> 2, c0 = (tid & 3) * 32;
        const __bf16* kp = kf + ((long)(bhl * 256 + s0 + r)) * FD + ch * 128 + c0;
#pragma unroll
        for (int j = 0; j < 4; ++j)
          *reinterpret_cast<bf16x8*>(&Kc[r][c0 + j * 8]) =
              *reinterpret_cast<const bf16x8*>(kp + j * 8);
      }
      __syncthreads();
#pragma unroll
      for (int kk = 0; kk < 4; ++kk) {
        const bf16x8 af = qreg[ch * 4 + kk];
#pragma unroll
        for (int c = 0; c < 4; ++c) {
          const bf16x8 bf = *reinterpret_cast<const bf16x8*>(&Kc[c * 16 + m][kk * 32 + q * 8]);
          sacc[c] = MFMA16(af, bf, sacc[c]);
        }
      }
    }
    // mask + C-layout -> A-layout via LDS (rows are wave-private: no barrier)
#pragma unroll
    for (int c = 0; c < 4; ++c)
#pragma unroll
      for (int r = 0; r < 4; ++r) {
        const int row = wv * 16 + q * 4 + r, col = c * 16 + m;
        Pt[row][col] = (__bf16)(((s0 + col) <= (t0 + row)) ? sacc[c][r] : 0.f);
      }
#pragma unroll
    for (int kk = 0; kk < 2; ++kk) {
      const bf16x8 pf = *reinterpret_cast<const bf16x8*>(&Pt[wv * 16 + m][kk * 32 + q * 8]);
#pragma unroll
      for (int c = 0; c < 5; ++c) {
        const bf16x8 vf = *reinterpret_cast<const bf16x8*>(&Vt[c * 16 + m][kk * 32 + q * 8]);
        oacc[c] = MFMA16(pf, vf, oacc[c]);
      }
    }
  }
#pragma unroll
  for (int r = 0; r < 4; ++r) {
    const float den = __shfl(oacc[4][r], (lane & 48));  // tile4 col0 = row denominator
    const float inv = 0.125f / (den + 1e-5f);           // SCALE=64^-0.5, EPS
    const int row = t0 + wv * 16 + q * 4 + r;
#pragma unroll
    for (int c = 0; c < 4; ++c)
      att[((long)(row * B_SZ + b)) * DM + h * DH + c * 16 + m] = (__bf16)(oacc[c][r] * inv);
  }
}

// ---------------------------------------------------------------------------
// K4: xrow = h + att @ w_o (f32), MFMA, Bt = w_o^T.
// ---------------------------------------------------------------------------
__global__ __launch_bounds__(256) void gemm_att_wo(const __bf16* __restrict__ A,
                                                   const __bf16* __restrict__ Bt,
                                                   const void* __restrict__ hin,
                                                   const int* __restrict__ flag,
                                                   float* __restrict__ xrow) {
  __shared__ __bf16 At[64][136];
  __shared__ __bf16 Bts[64][136];
  const int f32 = flag[0];
  const int n0 = blockIdx.x * 64, m0 = blockIdx.y * 64;
  const int tid = threadIdx.x, lane = tid & 63, wv = tid >> 6;
  const int m = lane & 15, q = lane >> 4;
  f32x4 acc[4];
#pragma unroll
  for (int i = 0; i < 4; ++i) acc[i] = f32x4{0.f, 0.f, 0.f, 0.f};

  for (int k0 = 0; k0 < DM; k0 += 128) {
    __syncthreads();
    {
      const int r = tid >> 2, c0 = (tid & 3) * 32;
#pragma unroll
      for (int j4 = 0; j4 < 4; ++j4) {
        *reinterpret_cast<bf16x8*>(&At[r][c0 + j4 * 8]) =
            *reinterpret_cast<const bf16x8*>(A + (long)(m0 + r) * DM + k0 + c0 + j4 * 8);
        *reinterpret_cast<bf16x8*>(&Bts[r][c0 + j4 * 8]) =
            *reinterpret_cast<const bf16x8*>(Bt + (long)(n0 + r) * DM + k0 + c0 + j4 * 8);
      }
    }
    __syncthreads();
#pragma unroll
    for (int kk = 0; kk < 4; ++kk) {
      const bf16x8 af = *reinterpret_cast<const bf16x8*>(&At[wv * 16 + m][kk * 32 + q * 8]);
#pragma unroll
      for (int c = 0; c < 4; ++c) {
        const bf16x8 bf = *reinterpret_cast<const bf16x8*>(&Bts[c * 16 + m][kk * 32 + q * 8]);
        acc[c] = MFMA16(af, bf, acc[c]);
      }
    }
  }
#pragma unroll
  for (int r = 0; r < 4; ++r)
#pragma unroll
    for (int c = 0; c < 4; ++c) {
      const long row = m0 + wv * 16 + q * 4 + r;
      const long col = n0 + c * 16 + m;
      xrow[row * DM + col] = acc[c][r] + ldmix(hin, row * DM + col, f32);
    }
}

// ---------------------------------------------------------------------------
// K5: LayerNorm rows of xrow -> out. One block per row.
// ---------------------------------------------------------------------------
__global__ __launch_bounds__(256) void ln_out(const float* __restrict__ xrow,
                                              const void* __restrict__ gamma,
                                              const void* __restrict__ beta,
                                              const int* __restrict__ flag,
                                              void* __restrict__ out) {
  const int f32 = flag[0];
  const int r = blockIdx.x;
  const int tid = threadIdx.x;
  __shared__ float red[256];
  const float x0 = xrow[(long)r * DM + tid];
  const float x1 = xrow[(long)r * DM + tid + 256];

  red[tid] = x0 + x1; __syncthreads();
  for (int s = 128; s > 0; s >>= 1) { if (tid < s) red[tid] += red[tid + s]; __syncthreads(); }
  const float mu = red[0] * (1.f / 512.f); __syncthreads();
  red[tid] = x0 * x0 + x1 * x1; __syncthreads();
  for (int s = 128; s > 0; s >>= 1) { if (tid < s) red[tid] += red[tid + s]; __syncthreads(); }
  const float var = red[0] * (1.f / 512.f) - mu * mu; __syncthreads();
  const float rstd = rsqrtf(var + 1e-5f);

  stmix(out, (long)r * DM + tid,
        (x0 - mu) * rstd * ldmix(gamma, tid, f32) + ldmix(beta, tid, f32), f32);
  stmix(out, (long)r * DM + tid + 256,
        (x1 - mu) * rstd * ldmix(gamma, tid + 256, f32) + ldmix(beta, tid + 256, f32), f32);
}

// ---------------------------------------------------------------------------
extern "C" void kernel_launch(void* const* d_in, const int* in_sizes, int n_in,
                              void* d_out, int out_size, void* d_ws, size_t ws_size,
                              hipStream_t stream) {
  (void)in_sizes; (void)n_in; (void)out_size;
  // Workspace layout (bytes):
  //   qkv  bf16 [8192,2048]   @ 0           33,554,432
  //   flag int                @ 33,554,432  256
  //   wt   bf16 [2048,512]    @ 33,554,688  2,097,152   (w_qkv^T)
  //   wot  bf16 [512,512]     @ 35,651,840  524,288     (w_o^T)
  //   att  bf16 [8192,512]    @ 36,176,128  8,388,608
  //   vt   bf16 [256,64,256]  @ 44,564,736  8,388,608
  //   R                       @ 52,953,344  qf/kf (2*64MB/G) then xrow f32 16.8MB
  char* ws = (char*)d_ws;
  __bf16* qkv = (__bf16*)ws;
  int* flag   = (int*)(ws + 33554432);
  __bf16* wt  = (__bf16*)(ws + 33554688);
  __bf16* wot = (__bf16*)(ws + 35651840);
  __bf16* att = (__bf16*)(ws + 36176128);
  __bf16* vt  = (__bf16*)(ws + 44564736);
  char* R     = ws + 52953344;
  float* xrow = (float*)R;               // aliases qf/kf (used after flash done)

  int G = 32;
  for (int g : {1, 2, 4, 8, 16, 32}) {
    unsigned long long need = 2ull * (67108864ull / (unsigned)g);
    if (need < 16777216ull) need = 16777216ull;
    if (52953344ull + need <= (unsigned long long)ws_size) { G = g; break; }
  }
  __bf16* qf = (__bf16*)R;
  __bf16* kf = qf + (33554432L / G);

  probe_dtype<<<1, 256, 0, stream>>>((const unsigned short*)d_in[0], flag);
  transpose_bf<<<dim3(32, 8), 256, 0, stream>>>(d_in[1], flag, wt, 512, 2048);
  transpose_bf<<<dim3(8, 8), 256, 0, stream>>>(d_in[2], flag, wot, 512, 512);
  gemm_h_wqkv<<<dim3(32, 128), 256, 0, stream>>>(d_in[0], flag, wt, qkv);
  vpack<<<dim3(4, 256), 256, 0, stream>>>(qkv, vt);

  const int nbh = 256 / G;
  for (int g = 0; g < G; ++g) {
    features<<<dim3(nbh * 256), 256, 0, stream>>>((const __hip_bfloat16*)qkv, d_in[7],
                                                  d_in[5], d_in[6], flag, g * nbh,
                                                  (__hip_bfloat16*)qf, (__hip_bfloat16*)kf);
    flash_mfma<<<dim3(4, nbh), 256, 0, stream>>>(qf, kf, vt, g * nbh, att);
  }
  gemm_att_wo<<<dim3(8, 128), 256, 0, stream>>>(att, wot, d_in[0], flag, xrow);
  ln_out<<<dim3(ROWS), 256, 0, stream>>>(xrow, d_in[3], d_in[4], flag, d_out);
}